// Round 1
// 2129.552 us; speedup vs baseline: 1.0298x; 1.0298x over previous
//
#include <hip/hip_runtime.h>
#include <stdint.h>

#define TT 2048
#define BB 128
#define DD 100
#define HH 100
#define GG 300   // 3*H, PyTorch gate order [r,z,n]
#define NT 31
#define NEGV (-10000.0f)

#define REP25(M) M(0) M(1) M(2) M(3) M(4) M(5) M(6) M(7) M(8) M(9) M(10) M(11) \
                 M(12) M(13) M(14) M(15) M(16) M(17) M(18) M(19) M(20) M(21) M(22) M(23) M(24)
#define REP31(M) M(0) M(1) M(2) M(3) M(4) M(5) M(6) M(7) M(8) M(9) M(10) M(11) \
                 M(12) M(13) M(14) M(15) M(16) M(17) M(18) M(19) M(20) M(21) M(22) M(23) \
                 M(24) M(25) M(26) M(27) M(28) M(29) M(30)
#define REP8(M)  M(0) M(1) M(2) M(3) M(4) M(5) M(6) M(7)

#define RL(v, k) __int_as_float(__builtin_amdgcn_readlane(__float_as_int(v), (k)))

typedef float f2 __attribute__((ext_vector_type(2)));

// ---------------------------------------------------------------------------
// Kernel 1: gi[dir][t][g] = x_dir(t) @ w_ih^T + b_ih  for batch row `seq`.
// ---------------------------------------------------------------------------
__global__ __launch_bounds__(320) void gi_kernel(
    const float* __restrict__ sent, const int* __restrict__ seqp,
    const float* __restrict__ w_ih_f, const float* __restrict__ b_ih_f,
    const float* __restrict__ w_ih_b, const float* __restrict__ b_ih_b,
    float* __restrict__ gi)
{
    const int t   = blockIdx.x;
    const int dir = blockIdx.y;
    const int j   = threadIdx.x;
    const int seq = seqp[0];
    const int ts  = dir ? (TT - 1 - t) : t;
    __shared__ __align__(16) float x_s[DD];
    if (j < DD) x_s[j] = sent[((size_t)ts * BB + seq) * DD + j];
    __syncthreads();
    if (j < GG) {
        const float* w = dir ? w_ih_b : w_ih_f;
        const float* b = dir ? b_ih_b : b_ih_f;
        const float4* w4 = (const float4*)(w + j * DD);
        const float4* x4 = (const float4*)x_s;
        float a0 = 0.f, a1 = 0.f, a2 = 0.f, a3 = 0.f;
        #pragma unroll
        for (int k = 0; k < DD / 4; k++) {
            float4 wv = w4[k], xv = x4[k];
            a0 += wv.x * xv.x; a1 += wv.y * xv.y;
            a2 += wv.z * xv.z; a3 += wv.w * xv.w;
        }
        gi[((size_t)dir * TT + t) * GG + j] = b[j] + (a0 + a1) + (a2 + a3);
    }
}

// ---------------------------------------------------------------------------
// Kernel 2: sequential GRU. 256 threads = 4 waves (1/SIMD).
// Wave q owns k-quarter q (k in [25q, 25q+25)) EXCLUSIVELY:
//   - activation for rows 25q..25q+24 computed ONCE (no A/B duplication)
//   - 25 readlane broadcasts per step per wave (was 25 per wave x 2 waves)
// Output slots are PAIRED: lane L carries pair-slots {L, 64+L, 128+L};
// pair P covers output rows (2P, 2P+1).  Each k contributes via ONE
// v_pk_fma_f32 per chain (2 FMAs/inst, broadcast h in an SGPR pair) ->
// 75 pk_fma per lane per step vs 150 scalar fma per SIMD before.
// Accumulation order per slot is identical to the scalar version
// (k ascending within quarter, quarters summed 0..3) -> bit-identical h.
// launch_bounds(256,1): full VGPR budget so all 150 weight floats stay
// register-resident (the old (512,2) cap forced them out: VGPR_Count 68 < 75).
// Slots 300..331 = fused w_out rows; wave 1 lanes 32..62 sum them to pfeat.
// ---------------------------------------------------------------------------
__global__ __launch_bounds__(256, 1) void gru_seq_kernel(
    const float* __restrict__ gi,
    const float* __restrict__ w_hh_f, const float* __restrict__ b_hh_f,
    const float* __restrict__ w_hh_b, const float* __restrict__ b_hh_b,
    const float* __restrict__ w_out,
    float* __restrict__ pfeat)           // [2][TT][NT], original time order
{
    const int dir  = blockIdx.x;
    const int tid  = threadIdx.x;
    const int wave = tid >> 6, lane = tid & 63;
    const int q    = wave;               // k-quarter owner
    const int k0   = q * 25;
    const float* w_hh = dir ? w_hh_b : w_hh_f;
    const float* b_hh = dir ? b_hh_b : b_hh_f;
    const float* gid  = gi + (size_t)dir * TT * GG;
    float* pf = pfeat + (size_t)dir * TT * NT;

    __shared__ __align__(16) float part[2][4][384];   // [buf][quarter][slot]

    const int P0 = lane, P1 = 64 + lane, P2 = 128 + lane;

    // row pointer for an output slot (gates from w_hh, 300+ from fused w_out;
    // dead slots >= 331 clamp to w_out row 30 harmlessly)
    auto rowp = [&](int s) -> const float* {
        if (s < GG) return w_hh + (size_t)s * DD + k0;
        int wr = s - GG; if (wr > NT - 1) wr = NT - 1;
        return w_out + (size_t)wr * (2 * HH) + dir * HH + k0;
    };
    const float* a0p = rowp(2 * P0);     const float* b0p = rowp(2 * P0 + 1);
    const float* a1p = rowp(2 * P1);     const float* b1p = rowp(2 * P1 + 1);
    const float* a2p = rowp(2 * P2);     const float* b2p = rowp(2 * P2 + 1);

    // ---- 75 named float2 weight pairs ----
    #define DECLW(i) f2 w0_##i, w1_##i, w2_##i;
    REP25(DECLW)
    #define LDW(i) w0_##i.x = a0p[i]; w0_##i.y = b0p[i]; \
                   w1_##i.x = a1p[i]; w1_##i.y = b1p[i]; \
                   w2_##i.x = a2p[i]; w2_##i.y = b2p[i];
    REP25(LDW)

    // ---- activation lanes: lane < 25, row r = k0 + lane ----
    const int r = k0 + lane;
    float bhr = 0.f, bhz = 0.f, bhn = 0.f;
    if (lane < 25) { bhr = b_hh[r]; bhz = b_hh[HH + r]; bhn = b_hh[2 * HH + r]; }

    // ---- pfeat lanes: wave 1, lanes 32..62 -> p = lane-32 ----
    const int  p     = lane - 32;
    const bool is_pf = (wave == 1) && (p >= 0) && (p < NT);
    #define DECLPH(i) float ph##i = 0.f;
    REP8(DECLPH)

    float hreg = 0.f;                    // lane L<25: h[k0+L]

    // gi prefetch pipeline depth 2 (act lanes only)
    float gAr = 0.f, gAz = 0.f, gAn = 0.f, gBr = 0.f, gBz = 0.f, gBn = 0.f;
    if (lane < 25) {
        gAr = gid[r];      gAz = gid[HH + r];      gAn = gid[2 * HH + r];
        gBr = gid[GG + r]; gBz = gid[GG + HH + r]; gBn = gid[GG + 2 * HH + r];
    }

    // one packed FMA: acc.{x,y} += w.{x,y} * h   (h broadcast via SGPR pair)
    #define PKFMA(ACC, W) asm("v_pk_fma_f32 %0, %1, %2, %0" \
                              : "+v"(ACC) : "v"(W), "s"(hp));

    #define DOTK(i) { unsigned hu = (unsigned)__builtin_amdgcn_readlane(        \
                          __float_as_int(hreg), (i));                           \
        uint64_t hp = ((uint64_t)hu << 32) | (uint64_t)hu;                      \
        PKFMA(acc0, w0_##i) PKFMA(acc1, w1_##i) PKFMA(acc2, w2_##i) }

    #define GRU_STEP(TIDX, BUF, SLOT, cr, cz, cn) {                          \
        f2 acc0 = {0.f, 0.f}, acc1 = {0.f, 0.f}, acc2 = {0.f, 0.f};          \
        REP25(DOTK)                                                          \
        *(f2*)&part[BUF][q][2 * P0] = acc0;                                  \
        *(f2*)&part[BUF][q][2 * P1] = acc1;                                  \
        *(f2*)&part[BUF][q][2 * P2] = acc2;                                  \
        __syncthreads();                                                     \
        if (lane < 25) {                                                     \
            float pr = part[BUF][0][r] + part[BUF][1][r]                     \
                     + part[BUF][2][r] + part[BUF][3][r];                    \
            float pz = part[BUF][0][HH + r] + part[BUF][1][HH + r]           \
                     + part[BUF][2][HH + r] + part[BUF][3][HH + r];          \
            float pn = part[BUF][0][2 * HH + r] + part[BUF][1][2 * HH + r]   \
                     + part[BUF][2][2 * HH + r] + part[BUF][3][2 * HH + r];  \
            float xr  = pr + bhr + (cr);                                     \
            float xz  = pz + bhz + (cz);                                     \
            float ghn = pn + bhn;                                            \
            float rr  = 1.f / (1.f + __expf(-xr));                           \
            float zz  = 1.f / (1.f + __expf(-xz));                           \
            float pre = (cn) + rr * ghn;                                     \
            pre = fmaxf(fminf(pre, 40.f), -40.f);                            \
            float e2  = __expf(-2.f * pre);                                  \
            float nn  = (1.f - e2) / (1.f + e2);                             \
            hreg = (1.f - zz) * nn + zz * hreg;                              \
            int tp = (TIDX) + 2; tp = (tp < TT) ? tp : (TT - 1);             \
            cr = gid[tp * GG + r];                                           \
            cz = gid[tp * GG + HH + r];                                      \
            cn = gid[tp * GG + 2 * HH + r];                                  \
        }                                                                    \
        if (is_pf && (TIDX) > 0) {                                           \
            ph##SLOT = part[BUF][0][GG + p] + part[BUF][1][GG + p]           \
                     + part[BUF][2][GG + p] + part[BUF][3][GG + p];          \
        }                                                                    \
    }

    #define PHST(i) pf[(size_t)(dir ? (TT - 1 - (tb + i)) : (tb + i)) * NT + p] = ph##i;

    for (int tt = 0; tt < TT; tt += 8) {
        GRU_STEP(tt + 0, 0, 7, gAr, gAz, gAn)
        if (is_pf && tt >= 8) { int tb = tt - 8; REP8(PHST) }
        GRU_STEP(tt + 1, 1, 0, gBr, gBz, gBn)
        GRU_STEP(tt + 2, 0, 1, gAr, gAz, gAn)
        GRU_STEP(tt + 3, 1, 2, gBr, gBz, gBn)
        GRU_STEP(tt + 4, 0, 3, gAr, gAz, gAn)
        GRU_STEP(tt + 5, 1, 4, gBr, gBz, gBn)
        GRU_STEP(tt + 6, 0, 5, gAr, gAz, gAn)
        GRU_STEP(tt + 7, 1, 6, gBr, gBz, gBn)
    }

    // ---- epilogue: feat of time TT-1 from final h (w_out chain only) ----
    {
        f2 acc2e = {0.f, 0.f};
        #define DOT2K(i) { unsigned hu = (unsigned)__builtin_amdgcn_readlane(   \
                              __float_as_int(hreg), (i));                       \
            uint64_t hp = ((uint64_t)hu << 32) | (uint64_t)hu;                  \
            PKFMA(acc2e, w2_##i) }
        REP25(DOT2K)
        *(f2*)&part[0][q][2 * P2] = acc2e;
        __syncthreads();
        if (is_pf) {
            ph7 = part[0][0][GG + p] + part[0][1][GG + p]
                + part[0][2][GG + p] + part[0][3][GG + p];
            int tb = TT - 8;
            REP8(PHST)
        }
    }
}

// ---------------------------------------------------------------------------
// Kernel 3a: serial Viterbi fv scan (values only; max is order-exact, so the
// max3-friendly ternary tree below is bit-identical to any other association).
// Single wave, zero barriers, trans row in named scalars.
// fvg[t] = fv BEFORE step t (slot 0 = init).
// ---------------------------------------------------------------------------
__global__ __launch_bounds__(64) void vit_scan_kernel(
    const float* __restrict__ pfeat, const float* __restrict__ mask,
    const int* __restrict__ seqp, const float* __restrict__ trans,
    const float* __restrict__ b_out,
    float* __restrict__ fvg, int* __restrict__ meta, float* __restrict__ out)
{
    const int lane = threadIdx.x;
    const int ln   = (lane < NT) ? lane : (NT - 1);   // clamped for loads
    const float* mrow = mask + (size_t)seqp[0] * TT;
    const float* pff = pfeat;
    const float* pfb = pfeat + (size_t)TT * NT;

    #define DECLTR(i) float tr##i = trans[ln * NT + i];
    REP31(DECLTR)
    const float bo = b_out[ln];

    float fv = (lane == 0) ? 0.f : NEGV;
    fvg[lane] = fv;                                   // slot 0 = init

    float ffr[8], fbr[8], mr[8];
    #pragma unroll
    for (int q = 0; q < 8; q++) {
        ffr[q] = pff[q * NT + ln]; fbr[q] = pfb[q * NT + ln]; mr[q] = mrow[q];
    }

    for (int t = 0; t < TT; t += 8) {
        #pragma unroll
        for (int q = 0; q < 8; q++) {
            float fcur = ffr[q] + fbr[q] + bo;
            float mcur = mr[q];
            int tp = t + q + 8; tp = (tp < TT) ? tp : (TT - 1);
            ffr[q] = pff[tp * NT + ln]; fbr[q] = pfb[tp * NT + ln]; mr[q] = mrow[tp];
            #define VADD(i) float v##i = RL(fv, i) + tr##i;
            REP31(VADD)
            #undef VADD
            // ternary max tree -> v_max3_f32 fusion (exact: max associates)
            float m0 = fmaxf(fmaxf(v0,  v1),  v2);
            float m1 = fmaxf(fmaxf(v3,  v4),  v5);
            float m2 = fmaxf(fmaxf(v6,  v7),  v8);
            float m3 = fmaxf(fmaxf(v9,  v10), v11);
            float m4 = fmaxf(fmaxf(v12, v13), v14);
            float m5 = fmaxf(fmaxf(v15, v16), v17);
            float m6 = fmaxf(fmaxf(v18, v19), v20);
            float m7 = fmaxf(fmaxf(v21, v22), v23);
            float m8 = fmaxf(fmaxf(v24, v25), v26);
            float m9 = fmaxf(fmaxf(v27, v28), v29);
            float n0 = fmaxf(fmaxf(m0, m1), m2);
            float n1 = fmaxf(fmaxf(m3, m4), m5);
            float n2 = fmaxf(fmaxf(m6, m7), m8);
            float m  = fmaxf(fmaxf(fmaxf(fmaxf(n0, n1), n2), m9), v30);
            float cand = m + fcur;
            fv = (mcur > 0.f) ? cand : fv;
            fvg[(t + q + 1) * 64 + lane] = fv;
        }
    }

    // final argmax, strict '>' ascending = first-max
    float fbest = RL(fv, 0);
    int ftag = 0;
    #pragma unroll
    for (int q = 1; q < NT; q++) {
        float s = RL(fv, q);
        if (s > fbest) { fbest = s; ftag = q; }
    }
    if (lane == 0) { out[0] = fbest; meta[0] = ftag; }
}

// ---------------------------------------------------------------------------
// Kernel 3b: parallel backpointer pass. Block b: t in [64b, 64b+64), 16 waves
// x 4 t's each. Recomputes argmax from stored fv (bit-exact same operands),
// exact first-max; wave 0 composes the block's 64 backpointer maps.
// ---------------------------------------------------------------------------
__global__ __launch_bounds__(1024) void vit_bp_kernel(
    const float* __restrict__ fvg, const float* __restrict__ mask,
    const int* __restrict__ seqp, const float* __restrict__ trans,
    uint8_t* __restrict__ bpg, uint8_t* __restrict__ gmapg)
{
    const int b    = blockIdx.x;
    const int tid  = threadIdx.x;
    const int wave = tid >> 6, lane = tid & 63;
    const int j    = lane & 31;
    const int jr   = (j < NT) ? j : (NT - 1);
    const float* mrow = mask + (size_t)seqp[0] * TT;

    __shared__ int bpl[64][32];

    float trj[NT];
    #pragma unroll
    for (int q = 0; q < NT; q++) trj[q] = trans[jr * NT + q];

    #pragma unroll
    for (int q4 = 0; q4 < 4; q4++) {
        const int t = b * 64 + wave * 4 + q4;
        float fvp = fvg[t * 64 + lane];          // lane p holds fv_prev[p]
        float mcur = mrow[t];
        float best = RL(fvp, 0) + trj[0];
        int bi = 0;
        #pragma unroll
        for (int q = 1; q < NT; q++) {
            float s = RL(fvp, q) + trj[q];
            if (s > best) { best = s; bi = q; }  // ascending strict '>' = first-max
        }
        int bpn = (mcur > 0.f) ? bi : j;
        if (j == 31) bpn = 31;
        if (lane < 32) {
            bpl[wave * 4 + q4][lane] = bpn;
            if (j < NT) bpg[(size_t)t * NT + j] = (uint8_t)bpn;
        }
    }
    __syncthreads();
    if (wave == 0) {
        int G = j;
        for (int i = 0; i < 64; i++) {
            int bpv = bpl[i][j];
            G = __shfl(G, bpv);                  // G_new[j] = G_old[bp_i[j]]
        }
        if (lane < 32) gmapg[b * 32 + lane] = (uint8_t)G;
    }
}

// ---------------------------------------------------------------------------
// Kernel 3c: backtrack. Loads all backpointers into LDS, composes the 32
// block maps serially (lane 0), then 32 lanes backtrack 64 steps each.
// ---------------------------------------------------------------------------
__global__ __launch_bounds__(64) void vit_back_kernel(
    const uint8_t* __restrict__ bpg, const uint8_t* __restrict__ gmapg,
    const int* __restrict__ meta, float* __restrict__ out)
{
    const int tid = threadIdx.x;
    __shared__ uint8_t bps[TT * NT];     // 63488 B
    __shared__ uint8_t gm[32 * 32];
    __shared__ uint8_t echk[32];

    const uint32_t* src = (const uint32_t*)bpg;
    uint32_t* dst = (uint32_t*)bps;
    for (int i = tid; i < TT * NT / 4; i += 64) dst[i] = src[i];
    for (int i = tid; i < 1024 / 4; i += 64)
        ((uint32_t*)gm)[i] = ((const uint32_t*)gmapg)[i];
    __syncthreads();

    if (tid == 0) {
        int tag = meta[0];
        for (int b = 31; b >= 0; b--) { echk[b] = (uint8_t)tag; tag = gm[b * 32 + tag]; }
    }
    __syncthreads();
    if (tid < 32) {
        int tag = echk[tid];
        for (int i = 63; i >= 0; i--) {
            int t = tid * 64 + i;
            out[1 + t] = (float)tag;
            tag = bps[t * NT + tag];
        }
    }
}

// ---------------------------------------------------------------------------
extern "C" void kernel_launch(void* const* d_in, const int* in_sizes, int n_in,
                              void* d_out, int out_size, void* d_ws, size_t ws_size,
                              hipStream_t stream) {
    const float* sent   = (const float*)d_in[0];
    const float* mask   = (const float*)d_in[1];
    const float* w_ih_f = (const float*)d_in[2];
    const float* w_hh_f = (const float*)d_in[3];
    const float* b_ih_f = (const float*)d_in[4];
    const float* b_hh_f = (const float*)d_in[5];
    const float* w_ih_b = (const float*)d_in[6];
    const float* w_hh_b = (const float*)d_in[7];
    const float* b_ih_b = (const float*)d_in[8];
    const float* b_hh_b = (const float*)d_in[9];
    const float* w_out  = (const float*)d_in[10];
    const float* b_out  = (const float*)d_in[11];
    const float* trans  = (const float*)d_in[12];
    const int*   seqp   = (const int*)d_in[14];
    float* out = (float*)d_out;

    // ws layout (floats): gi[2*TT*300] | pfeat[2*TT*31] | fvg[(TT+1)*64] |
    //                     bpg (TT*31 bytes) | gmapg (1024 bytes) | meta
    float* gi    = (float*)d_ws;
    float* pfeat = gi + (size_t)2 * TT * GG;
    float* fvg   = pfeat + (size_t)2 * TT * NT;
    float* bpf   = fvg + (size_t)(TT + 1) * 64;
    uint8_t* bpg   = (uint8_t*)bpf;
    uint8_t* gmapg = bpg + (size_t)TT * NT;
    int*     meta  = (int*)(gmapg + 1024);

    gi_kernel<<<dim3(TT, 2), 320, 0, stream>>>(sent, seqp, w_ih_f, b_ih_f,
                                               w_ih_b, b_ih_b, gi);
    gru_seq_kernel<<<2, 256, 0, stream>>>(gi, w_hh_f, b_hh_f, w_hh_b, b_hh_b,
                                          w_out, pfeat);
    vit_scan_kernel<<<1, 64, 0, stream>>>(pfeat, mask, seqp, trans, b_out,
                                          fvg, meta, out);
    vit_bp_kernel<<<32, 1024, 0, stream>>>(fvg, mask, seqp, trans, bpg, gmapg);
    vit_back_kernel<<<1, 64, 0, stream>>>(bpg, gmapg, meta, out);
}

// Round 2
// 2118.064 us; speedup vs baseline: 1.0353x; 1.0054x over previous
//
#include <hip/hip_runtime.h>
#include <stdint.h>

#define TT 2048
#define BB 128
#define DD 100
#define HH 100
#define GG 300   // 3*H, PyTorch gate order [r,z,n]
#define NT 31
#define NEGV (-10000.0f)

#define REP25(M) M(0) M(1) M(2) M(3) M(4) M(5) M(6) M(7) M(8) M(9) M(10) M(11) \
                 M(12) M(13) M(14) M(15) M(16) M(17) M(18) M(19) M(20) M(21) M(22) M(23) M(24)
#define REP31(M) M(0) M(1) M(2) M(3) M(4) M(5) M(6) M(7) M(8) M(9) M(10) M(11) \
                 M(12) M(13) M(14) M(15) M(16) M(17) M(18) M(19) M(20) M(21) M(22) M(23) \
                 M(24) M(25) M(26) M(27) M(28) M(29) M(30)
#define REP8(M)  M(0) M(1) M(2) M(3) M(4) M(5) M(6) M(7)

#define RL(v, k) __int_as_float(__builtin_amdgcn_readlane(__float_as_int(v), (k)))

typedef float f2 __attribute__((ext_vector_type(2)));

// Raw barrier: waits ONLY for LDS ops (the partial-sum ds_writes), NOT vmcnt.
// __syncthreads() would emit s_waitcnt vmcnt(0) and drain the gi prefetch
// pipeline every step (the ~1000-cycle/step stall R1's counters exposed:
// halving VALU issue left dur_us unchanged at 40% busy).  sched_barrier(0)
// on both sides pins ds_write above / ds_read below (rule #18).
#define BARRIER_LGKM() do {                                   \
    __builtin_amdgcn_sched_barrier(0);                        \
    asm volatile("s_waitcnt lgkmcnt(0)" ::: "memory");        \
    __builtin_amdgcn_s_barrier();                             \
    __builtin_amdgcn_sched_barrier(0);                        \
} while (0)

// ---------------------------------------------------------------------------
// Kernel 1: gi[dir][t][g] = x_dir(t) @ w_ih^T + b_ih  for batch row `seq`.
// ---------------------------------------------------------------------------
__global__ __launch_bounds__(320) void gi_kernel(
    const float* __restrict__ sent, const int* __restrict__ seqp,
    const float* __restrict__ w_ih_f, const float* __restrict__ b_ih_f,
    const float* __restrict__ w_ih_b, const float* __restrict__ b_ih_b,
    float* __restrict__ gi)
{
    const int t   = blockIdx.x;
    const int dir = blockIdx.y;
    const int j   = threadIdx.x;
    const int seq = seqp[0];
    const int ts  = dir ? (TT - 1 - t) : t;
    __shared__ __align__(16) float x_s[DD];
    if (j < DD) x_s[j] = sent[((size_t)ts * BB + seq) * DD + j];
    __syncthreads();
    if (j < GG) {
        const float* w = dir ? w_ih_b : w_ih_f;
        const float* b = dir ? b_ih_b : b_ih_f;
        const float4* w4 = (const float4*)(w + j * DD);
        const float4* x4 = (const float4*)x_s;
        float a0 = 0.f, a1 = 0.f, a2 = 0.f, a3 = 0.f;
        #pragma unroll
        for (int k = 0; k < DD / 4; k++) {
            float4 wv = w4[k], xv = x4[k];
            a0 += wv.x * xv.x; a1 += wv.y * xv.y;
            a2 += wv.z * xv.z; a3 += wv.w * xv.w;
        }
        gi[((size_t)dir * TT + t) * GG + j] = b[j] + (a0 + a1) + (a2 + a3);
    }
}

// ---------------------------------------------------------------------------
// Kernel 2: sequential GRU. 256 threads = 4 waves (1/SIMD).
// Wave q owns k-quarter q (k in [25q, 25q+25)) EXCLUSIVELY.
// Output slots are PAIRED: lane L carries pair-slots {L, 64+L, 128+L};
// pair P covers output rows (2P, 2P+1); one v_pk_fma_f32 per k per chain.
// Accumulation order per slot identical to the scalar version -> bit-exact.
// ONE lgkm-only barrier per step (ping-pong part buffers); global gi
// prefetch loads stay in flight across the barrier (counted vmcnt).
// Slots 300..331 = fused w_out rows; wave 1 lanes 32..62 sum them to pfeat.
// ---------------------------------------------------------------------------
__global__ __launch_bounds__(256, 1) void gru_seq_kernel(
    const float* __restrict__ gi,
    const float* __restrict__ w_hh_f, const float* __restrict__ b_hh_f,
    const float* __restrict__ w_hh_b, const float* __restrict__ b_hh_b,
    const float* __restrict__ w_out,
    float* __restrict__ pfeat)           // [2][TT][NT], original time order
{
    const int dir  = blockIdx.x;
    const int tid  = threadIdx.x;
    const int wave = tid >> 6, lane = tid & 63;
    const int q    = wave;               // k-quarter owner
    const int k0   = q * 25;
    const float* w_hh = dir ? w_hh_b : w_hh_f;
    const float* b_hh = dir ? b_hh_b : b_hh_f;
    const float* gid  = gi + (size_t)dir * TT * GG;
    float* pf = pfeat + (size_t)dir * TT * NT;

    __shared__ __align__(16) float part[2][4][384];   // [buf][quarter][slot]

    const int P0 = lane, P1 = 64 + lane, P2 = 128 + lane;

    // row pointer for an output slot (gates from w_hh, 300+ from fused w_out;
    // dead slots >= 331 clamp to w_out row 30 harmlessly)
    auto rowp = [&](int s) -> const float* {
        if (s < GG) return w_hh + (size_t)s * DD + k0;
        int wr = s - GG; if (wr > NT - 1) wr = NT - 1;
        return w_out + (size_t)wr * (2 * HH) + dir * HH + k0;
    };
    const float* a0p = rowp(2 * P0);     const float* b0p = rowp(2 * P0 + 1);
    const float* a1p = rowp(2 * P1);     const float* b1p = rowp(2 * P1 + 1);
    const float* a2p = rowp(2 * P2);     const float* b2p = rowp(2 * P2 + 1);

    // ---- 75 named float2 weight pairs ----
    #define DECLW(i) f2 w0_##i, w1_##i, w2_##i;
    REP25(DECLW)
    #define LDW(i) w0_##i.x = a0p[i]; w0_##i.y = b0p[i]; \
                   w1_##i.x = a1p[i]; w1_##i.y = b1p[i]; \
                   w2_##i.x = a2p[i]; w2_##i.y = b2p[i];
    REP25(LDW)

    // ---- activation lanes: lane < 25, row r = k0 + lane ----
    const int r = k0 + lane;
    float bhr = 0.f, bhz = 0.f, bhn = 0.f;
    if (lane < 25) { bhr = b_hh[r]; bhz = b_hh[HH + r]; bhn = b_hh[2 * HH + r]; }

    // ---- pfeat lanes: wave 1, lanes 32..62 -> p = lane-32 ----
    const int  p     = lane - 32;
    const bool is_pf = (wave == 1) && (p >= 0) && (p < NT);
    #define DECLPH(i) float ph##i = 0.f;
    REP8(DECLPH)

    float hreg = 0.f;                    // lane L<25: h[k0+L]

    // gi prefetch pipeline depth 2 (act lanes only)
    float gAr = 0.f, gAz = 0.f, gAn = 0.f, gBr = 0.f, gBz = 0.f, gBn = 0.f;
    if (lane < 25) {
        gAr = gid[r];      gAz = gid[HH + r];      gAn = gid[2 * HH + r];
        gBr = gid[GG + r]; gBz = gid[GG + HH + r]; gBn = gid[GG + 2 * HH + r];
    }

    // one packed FMA: acc.{x,y} += w.{x,y} * h   (h broadcast via SGPR pair)
    #define PKFMA(ACC, W) asm("v_pk_fma_f32 %0, %1, %2, %0" \
                              : "+v"(ACC) : "v"(W), "s"(hp));

    #define DOTK(i) { unsigned hu = (unsigned)__builtin_amdgcn_readlane(        \
                          __float_as_int(hreg), (i));                           \
        uint64_t hp = ((uint64_t)hu << 32) | (uint64_t)hu;                      \
        PKFMA(acc0, w0_##i) PKFMA(acc1, w1_##i) PKFMA(acc2, w2_##i) }

    #define GRU_STEP(TIDX, BUF, SLOT, cr, cz, cn) {                          \
        f2 acc0 = {0.f, 0.f}, acc1 = {0.f, 0.f}, acc2 = {0.f, 0.f};          \
        REP25(DOTK)                                                          \
        *(f2*)&part[BUF][q][2 * P0] = acc0;                                  \
        *(f2*)&part[BUF][q][2 * P1] = acc1;                                  \
        *(f2*)&part[BUF][q][2 * P2] = acc2;                                  \
        BARRIER_LGKM();                                                      \
        if (lane < 25) {                                                     \
            float pr = part[BUF][0][r] + part[BUF][1][r]                     \
                     + part[BUF][2][r] + part[BUF][3][r];                    \
            float pz = part[BUF][0][HH + r] + part[BUF][1][HH + r]           \
                     + part[BUF][2][HH + r] + part[BUF][3][HH + r];          \
            float pn = part[BUF][0][2 * HH + r] + part[BUF][1][2 * HH + r]   \
                     + part[BUF][2][2 * HH + r] + part[BUF][3][2 * HH + r];  \
            float xr  = pr + bhr + (cr);                                     \
            float xz  = pz + bhz + (cz);                                     \
            float ghn = pn + bhn;                                            \
            float rr  = 1.f / (1.f + __expf(-xr));                           \
            float zz  = 1.f / (1.f + __expf(-xz));                           \
            float pre = (cn) + rr * ghn;                                     \
            pre = fmaxf(fminf(pre, 40.f), -40.f);                            \
            float e2  = __expf(-2.f * pre);                                  \
            float nn  = (1.f - e2) / (1.f + e2);                             \
            hreg = (1.f - zz) * nn + zz * hreg;                              \
            int tp = (TIDX) + 2; tp = (tp < TT) ? tp : (TT - 1);             \
            cr = gid[tp * GG + r];                                           \
            cz = gid[tp * GG + HH + r];                                      \
            cn = gid[tp * GG + 2 * HH + r];                                  \
        }                                                                    \
        if (is_pf && (TIDX) > 0) {                                           \
            ph##SLOT = part[BUF][0][GG + p] + part[BUF][1][GG + p]           \
                     + part[BUF][2][GG + p] + part[BUF][3][GG + p];          \
        }                                                                    \
    }

    #define PHST(i) pf[(size_t)(dir ? (TT - 1 - (tb + i)) : (tb + i)) * NT + p] = ph##i;

    for (int tt = 0; tt < TT; tt += 8) {
        GRU_STEP(tt + 0, 0, 7, gAr, gAz, gAn)
        if (is_pf && tt >= 8) { int tb = tt - 8; REP8(PHST) }
        GRU_STEP(tt + 1, 1, 0, gBr, gBz, gBn)
        GRU_STEP(tt + 2, 0, 1, gAr, gAz, gAn)
        GRU_STEP(tt + 3, 1, 2, gBr, gBz, gBn)
        GRU_STEP(tt + 4, 0, 3, gAr, gAz, gAn)
        GRU_STEP(tt + 5, 1, 4, gBr, gBz, gBn)
        GRU_STEP(tt + 6, 0, 5, gAr, gAz, gAn)
        GRU_STEP(tt + 7, 1, 6, gBr, gBz, gBn)
    }

    // ---- epilogue: feat of time TT-1 from final h (w_out chain only) ----
    {
        f2 acc2e = {0.f, 0.f};
        #define DOT2K(i) { unsigned hu = (unsigned)__builtin_amdgcn_readlane(   \
                              __float_as_int(hreg), (i));                       \
            uint64_t hp = ((uint64_t)hu << 32) | (uint64_t)hu;                  \
            PKFMA(acc2e, w2_##i) }
        REP25(DOT2K)
        *(f2*)&part[0][q][2 * P2] = acc2e;
        BARRIER_LGKM();
        if (is_pf) {
            ph7 = part[0][0][GG + p] + part[0][1][GG + p]
                + part[0][2][GG + p] + part[0][3][GG + p];
            int tb = TT - 8;
            REP8(PHST)
        }
    }
}

// ---------------------------------------------------------------------------
// Kernel 3a: serial Viterbi fv scan (values only; max is order-exact, so the
// max3-friendly ternary tree below is bit-identical to any other association).
// Single wave, zero barriers, trans row in named scalars.
// fvg[t] = fv BEFORE step t (slot 0 = init).
// ---------------------------------------------------------------------------
__global__ __launch_bounds__(64) void vit_scan_kernel(
    const float* __restrict__ pfeat, const float* __restrict__ mask,
    const int* __restrict__ seqp, const float* __restrict__ trans,
    const float* __restrict__ b_out,
    float* __restrict__ fvg, int* __restrict__ meta, float* __restrict__ out)
{
    const int lane = threadIdx.x;
    const int ln   = (lane < NT) ? lane : (NT - 1);   // clamped for loads
    const float* mrow = mask + (size_t)seqp[0] * TT;
    const float* pff = pfeat;
    const float* pfb = pfeat + (size_t)TT * NT;

    #define DECLTR(i) float tr##i = trans[ln * NT + i];
    REP31(DECLTR)
    const float bo = b_out[ln];

    float fv = (lane == 0) ? 0.f : NEGV;
    fvg[lane] = fv;                                   // slot 0 = init

    float ffr[8], fbr[8], mr[8];
    #pragma unroll
    for (int q = 0; q < 8; q++) {
        ffr[q] = pff[q * NT + ln]; fbr[q] = pfb[q * NT + ln]; mr[q] = mrow[q];
    }

    for (int t = 0; t < TT; t += 8) {
        #pragma unroll
        for (int q = 0; q < 8; q++) {
            float fcur = ffr[q] + fbr[q] + bo;
            float mcur = mr[q];
            int tp = t + q + 8; tp = (tp < TT) ? tp : (TT - 1);
            ffr[q] = pff[tp * NT + ln]; fbr[q] = pfb[tp * NT + ln]; mr[q] = mrow[tp];
            #define VADD(i) float v##i = RL(fv, i) + tr##i;
            REP31(VADD)
            #undef VADD
            // ternary max tree -> v_max3_f32 fusion (exact: max associates)
            float m0 = fmaxf(fmaxf(v0,  v1),  v2);
            float m1 = fmaxf(fmaxf(v3,  v4),  v5);
            float m2 = fmaxf(fmaxf(v6,  v7),  v8);
            float m3 = fmaxf(fmaxf(v9,  v10), v11);
            float m4 = fmaxf(fmaxf(v12, v13), v14);
            float m5 = fmaxf(fmaxf(v15, v16), v17);
            float m6 = fmaxf(fmaxf(v18, v19), v20);
            float m7 = fmaxf(fmaxf(v21, v22), v23);
            float m8 = fmaxf(fmaxf(v24, v25), v26);
            float m9 = fmaxf(fmaxf(v27, v28), v29);
            float n0 = fmaxf(fmaxf(m0, m1), m2);
            float n1 = fmaxf(fmaxf(m3, m4), m5);
            float n2 = fmaxf(fmaxf(m6, m7), m8);
            float m  = fmaxf(fmaxf(fmaxf(fmaxf(n0, n1), n2), m9), v30);
            float cand = m + fcur;
            fv = (mcur > 0.f) ? cand : fv;
            fvg[(t + q + 1) * 64 + lane] = fv;
        }
    }

    // final argmax, strict '>' ascending = first-max
    float fbest = RL(fv, 0);
    int ftag = 0;
    #pragma unroll
    for (int q = 1; q < NT; q++) {
        float s = RL(fv, q);
        if (s > fbest) { fbest = s; ftag = q; }
    }
    if (lane == 0) { out[0] = fbest; meta[0] = ftag; }
}

// ---------------------------------------------------------------------------
// Kernel 3b: parallel backpointer pass. Block b: t in [64b, 64b+64), 16 waves
// x 4 t's each. Recomputes argmax from stored fv (bit-exact same operands),
// exact first-max; wave 0 composes the block's 64 backpointer maps.
// ---------------------------------------------------------------------------
__global__ __launch_bounds__(1024) void vit_bp_kernel(
    const float* __restrict__ fvg, const float* __restrict__ mask,
    const int* __restrict__ seqp, const float* __restrict__ trans,
    uint8_t* __restrict__ bpg, uint8_t* __restrict__ gmapg)
{
    const int b    = blockIdx.x;
    const int tid  = threadIdx.x;
    const int wave = tid >> 6, lane = tid & 63;
    const int j    = lane & 31;
    const int jr   = (j < NT) ? j : (NT - 1);
    const float* mrow = mask + (size_t)seqp[0] * TT;

    __shared__ int bpl[64][32];

    float trj[NT];
    #pragma unroll
    for (int q = 0; q < NT; q++) trj[q] = trans[jr * NT + q];

    #pragma unroll
    for (int q4 = 0; q4 < 4; q4++) {
        const int t = b * 64 + wave * 4 + q4;
        float fvp = fvg[t * 64 + lane];          // lane p holds fv_prev[p]
        float mcur = mrow[t];
        float best = RL(fvp, 0) + trj[0];
        int bi = 0;
        #pragma unroll
        for (int q = 1; q < NT; q++) {
            float s = RL(fvp, q) + trj[q];
            if (s > best) { best = s; bi = q; }  // ascending strict '>' = first-max
        }
        int bpn = (mcur > 0.f) ? bi : j;
        if (j == 31) bpn = 31;
        if (lane < 32) {
            bpl[wave * 4 + q4][lane] = bpn;
            if (j < NT) bpg[(size_t)t * NT + j] = (uint8_t)bpn;
        }
    }
    __syncthreads();
    if (wave == 0) {
        int G = j;
        for (int i = 0; i < 64; i++) {
            int bpv = bpl[i][j];
            G = __shfl(G, bpv);                  // G_new[j] = G_old[bp_i[j]]
        }
        if (lane < 32) gmapg[b * 32 + lane] = (uint8_t)G;
    }
}

// ---------------------------------------------------------------------------
// Kernel 3c: backtrack. Loads all backpointers into LDS, composes the 32
// block maps serially (lane 0), then 32 lanes backtrack 64 steps each.
// ---------------------------------------------------------------------------
__global__ __launch_bounds__(64) void vit_back_kernel(
    const uint8_t* __restrict__ bpg, const uint8_t* __restrict__ gmapg,
    const int* __restrict__ meta, float* __restrict__ out)
{
    const int tid = threadIdx.x;
    __shared__ uint8_t bps[TT * NT];     // 63488 B
    __shared__ uint8_t gm[32 * 32];
    __shared__ uint8_t echk[32];

    const uint32_t* src = (const uint32_t*)bpg;
    uint32_t* dst = (uint32_t*)bps;
    for (int i = tid; i < TT * NT / 4; i += 64) dst[i] = src[i];
    for (int i = tid; i < 1024 / 4; i += 64)
        ((uint32_t*)gm)[i] = ((const uint32_t*)gmapg)[i];
    __syncthreads();

    if (tid == 0) {
        int tag = meta[0];
        for (int b = 31; b >= 0; b--) { echk[b] = (uint8_t)tag; tag = gm[b * 32 + tag]; }
    }
    __syncthreads();
    if (tid < 32) {
        int tag = echk[tid];
        for (int i = 63; i >= 0; i--) {
            int t = tid * 64 + i;
            out[1 + t] = (float)tag;
            tag = bps[t * NT + tag];
        }
    }
}

// ---------------------------------------------------------------------------
extern "C" void kernel_launch(void* const* d_in, const int* in_sizes, int n_in,
                              void* d_out, int out_size, void* d_ws, size_t ws_size,
                              hipStream_t stream) {
    const float* sent   = (const float*)d_in[0];
    const float* mask   = (const float*)d_in[1];
    const float* w_ih_f = (const float*)d_in[2];
    const float* w_hh_f = (const float*)d_in[3];
    const float* b_ih_f = (const float*)d_in[4];
    const float* b_hh_f = (const float*)d_in[5];
    const float* w_ih_b = (const float*)d_in[6];
    const float* w_hh_b = (const float*)d_in[7];
    const float* b_ih_b = (const float*)d_in[8];
    const float* b_hh_b = (const float*)d_in[9];
    const float* w_out  = (const float*)d_in[10];
    const float* b_out  = (const float*)d_in[11];
    const float* trans  = (const float*)d_in[12];
    const int*   seqp   = (const int*)d_in[14];
    float* out = (float*)d_out;

    // ws layout (floats): gi[2*TT*300] | pfeat[2*TT*31] | fvg[(TT+1)*64] |
    //                     bpg (TT*31 bytes) | gmapg (1024 bytes) | meta
    float* gi    = (float*)d_ws;
    float* pfeat = gi + (size_t)2 * TT * GG;
    float* fvg   = pfeat + (size_t)2 * TT * NT;
    float* bpf   = fvg + (size_t)(TT + 1) * 64;
    uint8_t* bpg   = (uint8_t*)bpf;
    uint8_t* gmapg = bpg + (size_t)TT * NT;
    int*     meta  = (int*)(gmapg + 1024);

    gi_kernel<<<dim3(TT, 2), 320, 0, stream>>>(sent, seqp, w_ih_f, b_ih_f,
                                               w_ih_b, b_ih_b, gi);
    gru_seq_kernel<<<2, 256, 0, stream>>>(gi, w_hh_f, b_hh_f, w_hh_b, b_hh_b,
                                          w_out, pfeat);
    vit_scan_kernel<<<1, 64, 0, stream>>>(pfeat, mask, seqp, trans, b_out,
                                          fvg, meta, out);
    vit_bp_kernel<<<32, 1024, 0, stream>>>(fvg, mask, seqp, trans, bpg, gmapg);
    vit_back_kernel<<<1, 64, 0, stream>>>(bpg, gmapg, meta, out);
}

// Round 3
// 1798.698 us; speedup vs baseline: 1.2192x; 1.1776x over previous
//
#include <hip/hip_runtime.h>
#include <stdint.h>

#define TT 2048
#define BB 128
#define DD 100
#define HH 100
#define GG 300   // 3*H, PyTorch gate order [r,z,n]
#define NT 31
#define NEGV (-10000.0f)

#define REP25(M) M(0) M(1) M(2) M(3) M(4) M(5) M(6) M(7) M(8) M(9) M(10) M(11) \
                 M(12) M(13) M(14) M(15) M(16) M(17) M(18) M(19) M(20) M(21) M(22) M(23) M(24)
#define REP31(M) M(0) M(1) M(2) M(3) M(4) M(5) M(6) M(7) M(8) M(9) M(10) M(11) \
                 M(12) M(13) M(14) M(15) M(16) M(17) M(18) M(19) M(20) M(21) M(22) M(23) \
                 M(24) M(25) M(26) M(27) M(28) M(29) M(30)
#define REP8(M)  M(0) M(1) M(2) M(3) M(4) M(5) M(6) M(7)

#define RL(v, k) __int_as_float(__builtin_amdgcn_readlane(__float_as_int(v), (k)))

typedef float f2 __attribute__((ext_vector_type(2)));

// Raw barrier: waits ONLY for LDS ops (the partial-sum ds_writes), NOT vmcnt,
// so the gi prefetch loads stay in flight across steps.
#define BARRIER_LGKM() do {                                   \
    __builtin_amdgcn_sched_barrier(0);                        \
    asm volatile("s_waitcnt lgkmcnt(0)" ::: "memory");        \
    __builtin_amdgcn_s_barrier();                             \
    __builtin_amdgcn_sched_barrier(0);                        \
} while (0)

// ---------------------------------------------------------------------------
// Kernel 1: gi[dir][t][g] = x_dir(t) @ w_ih^T + b_ih  for batch row `seq`.
// ---------------------------------------------------------------------------
__global__ __launch_bounds__(320) void gi_kernel(
    const float* __restrict__ sent, const int* __restrict__ seqp,
    const float* __restrict__ w_ih_f, const float* __restrict__ b_ih_f,
    const float* __restrict__ w_ih_b, const float* __restrict__ b_ih_b,
    float* __restrict__ gi)
{
    const int t   = blockIdx.x;
    const int dir = blockIdx.y;
    const int j   = threadIdx.x;
    const int seq = seqp[0];
    const int ts  = dir ? (TT - 1 - t) : t;
    __shared__ __align__(16) float x_s[DD];
    if (j < DD) x_s[j] = sent[((size_t)ts * BB + seq) * DD + j];
    __syncthreads();
    if (j < GG) {
        const float* w = dir ? w_ih_b : w_ih_f;
        const float* b = dir ? b_ih_b : b_ih_f;
        const float4* w4 = (const float4*)(w + j * DD);
        const float4* x4 = (const float4*)x_s;
        float a0 = 0.f, a1 = 0.f, a2 = 0.f, a3 = 0.f;
        #pragma unroll
        for (int k = 0; k < DD / 4; k++) {
            float4 wv = w4[k], xv = x4[k];
            a0 += wv.x * xv.x; a1 += wv.y * xv.y;
            a2 += wv.z * xv.z; a3 += wv.w * xv.w;
        }
        gi[((size_t)dir * TT + t) * GG + j] = b[j] + (a0 + a1) + (a2 + a3);
    }
}

// ---------------------------------------------------------------------------
// Kernel 2: sequential GRU. 256 threads = 4 waves (1/SIMD).
// Wave q owns k-quarter q (k in [25q, 25q+25)) EXCLUSIVELY.
// h-BROADCAST VIA LDS (this round's change): the act lanes ds_write hreg to a
// per-quarter LDS array hsh[q]; the dot reads it as broadcast ds_read_b64
// (same address across lanes = conflict-free) feeding v_pk_fma_f32 with
// VOP3P op_sel lo/hi broadcast.  This removes the 25x serial
// (v_readlane -> SGPR build -> pk_fma) hazard chain that R0-R2's identical
// 1537us wall (invariant to issue count AND barrier policy) implicates.
// Same-wave write->read ordering via lgkmcnt: NO extra barrier.
// Accumulation order per chain is still k=0..24 ascending -> bit-exact.
// ---------------------------------------------------------------------------
__global__ __launch_bounds__(256, 1) void gru_seq_kernel(
    const float* __restrict__ gi,
    const float* __restrict__ w_hh_f, const float* __restrict__ b_hh_f,
    const float* __restrict__ w_hh_b, const float* __restrict__ b_hh_b,
    const float* __restrict__ w_out,
    float* __restrict__ pfeat)           // [2][TT][NT], original time order
{
    const int dir  = blockIdx.x;
    const int tid  = threadIdx.x;
    const int wave = tid >> 6, lane = tid & 63;
    const int q    = wave;               // k-quarter owner
    const int k0   = q * 25;
    const float* w_hh = dir ? w_hh_b : w_hh_f;
    const float* b_hh = dir ? b_hh_b : b_hh_f;
    const float* gid  = gi + (size_t)dir * TT * GG;
    float* pf = pfeat + (size_t)dir * TT * NT;

    __shared__ __align__(16) float part[2][4][384];   // [buf][quarter][slot]
    __shared__ __align__(16) float hsh[4 * 28];       // per-quarter h, 8B-aligned base

    const int P0 = lane, P1 = 64 + lane, P2 = 128 + lane;
    const int hb = q * 28;

    // row pointer for an output slot (gates from w_hh, 300+ from fused w_out;
    // dead slots >= 331 clamp to w_out row 30 harmlessly)
    auto rowp = [&](int s) -> const float* {
        if (s < GG) return w_hh + (size_t)s * DD + k0;
        int wr = s - GG; if (wr > NT - 1) wr = NT - 1;
        return w_out + (size_t)wr * (2 * HH) + dir * HH + k0;
    };
    const float* a0p = rowp(2 * P0);     const float* b0p = rowp(2 * P0 + 1);
    const float* a1p = rowp(2 * P1);     const float* b1p = rowp(2 * P1 + 1);
    const float* a2p = rowp(2 * P2);     const float* b2p = rowp(2 * P2 + 1);

    // ---- 75 named float2 weight pairs (pair across ROWS, indexed by k) ----
    #define DECLW(i) f2 w0_##i, w1_##i, w2_##i;
    REP25(DECLW)
    #define LDW(i) w0_##i.x = a0p[i]; w0_##i.y = b0p[i]; \
                   w1_##i.x = a1p[i]; w1_##i.y = b1p[i]; \
                   w2_##i.x = a2p[i]; w2_##i.y = b2p[i];
    REP25(LDW)

    // ---- activation lanes: lane < 25, row r = k0 + lane ----
    const int r = k0 + lane;
    float bhr = 0.f, bhz = 0.f, bhn = 0.f;
    if (lane < 25) { bhr = b_hh[r]; bhz = b_hh[HH + r]; bhn = b_hh[2 * HH + r]; }

    // ---- pfeat lanes: wave 1, lanes 32..62 -> p = lane-32 ----
    const int  p     = lane - 32;
    const bool is_pf = (wave == 1) && (p >= 0) && (p < NT);
    #define DECLPH(i) float ph##i = 0.f;
    REP8(DECLPH)

    float hreg = 0.f;                    // lane L<25: h[k0+L]
    if (lane < 25) hsh[hb + lane] = 0.f; // h(0) = 0 visible to own wave's dot

    // gi prefetch pipeline depth 2 (act lanes only)
    float gAr = 0.f, gAz = 0.f, gAn = 0.f, gBr = 0.f, gBz = 0.f, gBn = 0.f;
    if (lane < 25) {
        gAr = gid[r];      gAz = gid[HH + r];      gAn = gid[2 * HH + r];
        gBr = gid[GG + r]; gBz = gid[GG + HH + r]; gBn = gid[GG + 2 * HH + r];
    }

    // VOP3P broadcast FMAs: both result halves use src1.lo (resp .hi).
    #define PKFMA_LO(ACC, W, H) asm("v_pk_fma_f32 %0, %1, %2, %0 op_sel:[0,0,0] op_sel_hi:[1,0,1]" \
                                    : "+v"(ACC) : "v"(W), "v"(H));
    #define PKFMA_HI(ACC, W, H) asm("v_pk_fma_f32 %0, %1, %2, %0 op_sel:[0,1,0] op_sel_hi:[1,1,1]" \
                                    : "+v"(ACC) : "v"(W), "v"(H));

    #define PAIRS(M) M(0,0,1) M(1,2,3) M(2,4,5) M(3,6,7) M(4,8,9) M(5,10,11) \
                     M(6,12,13) M(7,14,15) M(8,16,17) M(9,18,19) M(10,20,21) M(11,22,23)

    #define DOTP(s, ka, kb) { f2 hv = *(const f2*)&hsh[hb + 2 * (s)];        \
        PKFMA_LO(acc0, w0_##ka, hv) PKFMA_LO(acc1, w1_##ka, hv)              \
        PKFMA_LO(acc2, w2_##ka, hv)                                          \
        PKFMA_HI(acc0, w0_##kb, hv) PKFMA_HI(acc1, w1_##kb, hv)              \
        PKFMA_HI(acc2, w2_##kb, hv) }
    // k=24: b64 read of (h24, pad) -- pad half never enters math (lo bcast)
    #define DOTLAST { f2 hv = *(const f2*)&hsh[hb + 24];                     \
        PKFMA_LO(acc0, w0_24, hv) PKFMA_LO(acc1, w1_24, hv)                  \
        PKFMA_LO(acc2, w2_24, hv) }

    #define GRU_STEP(TIDX, BUF, SLOT, cr, cz, cn) {                          \
        f2 acc0 = {0.f, 0.f}, acc1 = {0.f, 0.f}, acc2 = {0.f, 0.f};          \
        PAIRS(DOTP)                                                          \
        DOTLAST                                                              \
        *(f2*)&part[BUF][q][2 * P0] = acc0;                                  \
        *(f2*)&part[BUF][q][2 * P1] = acc1;                                  \
        *(f2*)&part[BUF][q][2 * P2] = acc2;                                  \
        BARRIER_LGKM();                                                      \
        if (lane < 25) {                                                     \
            float pr = part[BUF][0][r] + part[BUF][1][r]                     \
                     + part[BUF][2][r] + part[BUF][3][r];                    \
            float pz = part[BUF][0][HH + r] + part[BUF][1][HH + r]           \
                     + part[BUF][2][HH + r] + part[BUF][3][HH + r];          \
            float pn = part[BUF][0][2 * HH + r] + part[BUF][1][2 * HH + r]   \
                     + part[BUF][2][2 * HH + r] + part[BUF][3][2 * HH + r];  \
            float xr  = pr + bhr + (cr);                                     \
            float xz  = pz + bhz + (cz);                                     \
            float ghn = pn + bhn;                                            \
            float rr  = 1.f / (1.f + __expf(-xr));                           \
            float zz  = 1.f / (1.f + __expf(-xz));                           \
            float pre = (cn) + rr * ghn;                                     \
            pre = fmaxf(fminf(pre, 40.f), -40.f);                            \
            float e2  = __expf(-2.f * pre);                                  \
            float nn  = (1.f - e2) / (1.f + e2);                             \
            hreg = (1.f - zz) * nn + zz * hreg;                              \
            hsh[hb + lane] = hreg;                                           \
            int tp = (TIDX) + 2; tp = (tp < TT) ? tp : (TT - 1);             \
            cr = gid[tp * GG + r];                                           \
            cz = gid[tp * GG + HH + r];                                      \
            cn = gid[tp * GG + 2 * HH + r];                                  \
        }                                                                    \
        if (is_pf && (TIDX) > 0) {                                           \
            ph##SLOT = part[BUF][0][GG + p] + part[BUF][1][GG + p]           \
                     + part[BUF][2][GG + p] + part[BUF][3][GG + p];          \
        }                                                                    \
    }

    #define PHST(i) pf[(size_t)(dir ? (TT - 1 - (tb + i)) : (tb + i)) * NT + p] = ph##i;

    for (int tt = 0; tt < TT; tt += 8) {
        GRU_STEP(tt + 0, 0, 7, gAr, gAz, gAn)
        if (is_pf && tt >= 8) { int tb = tt - 8; REP8(PHST) }
        GRU_STEP(tt + 1, 1, 0, gBr, gBz, gBn)
        GRU_STEP(tt + 2, 0, 1, gAr, gAz, gAn)
        GRU_STEP(tt + 3, 1, 2, gBr, gBz, gBn)
        GRU_STEP(tt + 4, 0, 3, gAr, gAz, gAn)
        GRU_STEP(tt + 5, 1, 4, gBr, gBz, gBn)
        GRU_STEP(tt + 6, 0, 5, gAr, gAz, gAn)
        GRU_STEP(tt + 7, 1, 6, gBr, gBz, gBn)
    }

    // ---- epilogue: feat of time TT-1 from final h (w_out chain only) ----
    {
        f2 acc2e = {0.f, 0.f};
        #define DOT2P(s, ka, kb) { f2 hv = *(const f2*)&hsh[hb + 2 * (s)];   \
            PKFMA_LO(acc2e, w2_##ka, hv) PKFMA_HI(acc2e, w2_##kb, hv) }
        PAIRS(DOT2P)
        { f2 hv = *(const f2*)&hsh[hb + 24]; PKFMA_LO(acc2e, w2_24, hv) }
        *(f2*)&part[0][q][2 * P2] = acc2e;
        BARRIER_LGKM();
        if (is_pf) {
            ph7 = part[0][0][GG + p] + part[0][1][GG + p]
                + part[0][2][GG + p] + part[0][3][GG + p];
            int tb = TT - 8;
            REP8(PHST)
        }
    }
}

// ---------------------------------------------------------------------------
// Kernel 3a: serial Viterbi fv scan (values only; max is order-exact, so the
// max3-friendly ternary tree below is bit-identical to any other association).
// Single wave, zero barriers, trans row in named scalars.
// fvg[t] = fv BEFORE step t (slot 0 = init).
// ---------------------------------------------------------------------------
__global__ __launch_bounds__(64) void vit_scan_kernel(
    const float* __restrict__ pfeat, const float* __restrict__ mask,
    const int* __restrict__ seqp, const float* __restrict__ trans,
    const float* __restrict__ b_out,
    float* __restrict__ fvg, int* __restrict__ meta, float* __restrict__ out)
{
    const int lane = threadIdx.x;
    const int ln   = (lane < NT) ? lane : (NT - 1);   // clamped for loads
    const float* mrow = mask + (size_t)seqp[0] * TT;
    const float* pff = pfeat;
    const float* pfb = pfeat + (size_t)TT * NT;

    #define DECLTR(i) float tr##i = trans[ln * NT + i];
    REP31(DECLTR)
    const float bo = b_out[ln];

    float fv = (lane == 0) ? 0.f : NEGV;
    fvg[lane] = fv;                                   // slot 0 = init

    float ffr[8], fbr[8], mr[8];
    #pragma unroll
    for (int q = 0; q < 8; q++) {
        ffr[q] = pff[q * NT + ln]; fbr[q] = pfb[q * NT + ln]; mr[q] = mrow[q];
    }

    for (int t = 0; t < TT; t += 8) {
        #pragma unroll
        for (int q = 0; q < 8; q++) {
            float fcur = ffr[q] + fbr[q] + bo;
            float mcur = mr[q];
            int tp = t + q + 8; tp = (tp < TT) ? tp : (TT - 1);
            ffr[q] = pff[tp * NT + ln]; fbr[q] = pfb[tp * NT + ln]; mr[q] = mrow[tp];
            #define VADD(i) float v##i = RL(fv, i) + tr##i;
            REP31(VADD)
            #undef VADD
            // ternary max tree -> v_max3_f32 fusion (exact: max associates)
            float m0 = fmaxf(fmaxf(v0,  v1),  v2);
            float m1 = fmaxf(fmaxf(v3,  v4),  v5);
            float m2 = fmaxf(fmaxf(v6,  v7),  v8);
            float m3 = fmaxf(fmaxf(v9,  v10), v11);
            float m4 = fmaxf(fmaxf(v12, v13), v14);
            float m5 = fmaxf(fmaxf(v15, v16), v17);
            float m6 = fmaxf(fmaxf(v18, v19), v20);
            float m7 = fmaxf(fmaxf(v21, v22), v23);
            float m8 = fmaxf(fmaxf(v24, v25), v26);
            float m9 = fmaxf(fmaxf(v27, v28), v29);
            float n0 = fmaxf(fmaxf(m0, m1), m2);
            float n1 = fmaxf(fmaxf(m3, m4), m5);
            float n2 = fmaxf(fmaxf(m6, m7), m8);
            float m  = fmaxf(fmaxf(fmaxf(fmaxf(n0, n1), n2), m9), v30);
            float cand = m + fcur;
            fv = (mcur > 0.f) ? cand : fv;
            fvg[(t + q + 1) * 64 + lane] = fv;
        }
    }

    // final argmax, strict '>' ascending = first-max
    float fbest = RL(fv, 0);
    int ftag = 0;
    #pragma unroll
    for (int q = 1; q < NT; q++) {
        float s = RL(fv, q);
        if (s > fbest) { fbest = s; ftag = q; }
    }
    if (lane == 0) { out[0] = fbest; meta[0] = ftag; }
}

// ---------------------------------------------------------------------------
// Kernel 3b: parallel backpointer pass. Block b: t in [64b, 64b+64), 16 waves
// x 4 t's each. Recomputes argmax from stored fv (bit-exact same operands),
// exact first-max; wave 0 composes the block's 64 backpointer maps.
// ---------------------------------------------------------------------------
__global__ __launch_bounds__(1024) void vit_bp_kernel(
    const float* __restrict__ fvg, const float* __restrict__ mask,
    const int* __restrict__ seqp, const float* __restrict__ trans,
    uint8_t* __restrict__ bpg, uint8_t* __restrict__ gmapg)
{
    const int b    = blockIdx.x;
    const int tid  = threadIdx.x;
    const int wave = tid >> 6, lane = tid & 63;
    const int j    = lane & 31;
    const int jr   = (j < NT) ? j : (NT - 1);
    const float* mrow = mask + (size_t)seqp[0] * TT;

    __shared__ int bpl[64][32];

    float trj[NT];
    #pragma unroll
    for (int q = 0; q < NT; q++) trj[q] = trans[jr * NT + q];

    #pragma unroll
    for (int q4 = 0; q4 < 4; q4++) {
        const int t = b * 64 + wave * 4 + q4;
        float fvp = fvg[t * 64 + lane];          // lane p holds fv_prev[p]
        float mcur = mrow[t];
        float best = RL(fvp, 0) + trj[0];
        int bi = 0;
        #pragma unroll
        for (int q = 1; q < NT; q++) {
            float s = RL(fvp, q) + trj[q];
            if (s > best) { best = s; bi = q; }  // ascending strict '>' = first-max
        }
        int bpn = (mcur > 0.f) ? bi : j;
        if (j == 31) bpn = 31;
        if (lane < 32) {
            bpl[wave * 4 + q4][lane] = bpn;
            if (j < NT) bpg[(size_t)t * NT + j] = (uint8_t)bpn;
        }
    }
    __syncthreads();
    if (wave == 0) {
        int G = j;
        for (int i = 0; i < 64; i++) {
            int bpv = bpl[i][j];
            G = __shfl(G, bpv);                  // G_new[j] = G_old[bp_i[j]]
        }
        if (lane < 32) gmapg[b * 32 + lane] = (uint8_t)G;
    }
}

// ---------------------------------------------------------------------------
// Kernel 3c: backtrack. Loads all backpointers into LDS, composes the 32
// block maps serially (lane 0), then 32 lanes backtrack 64 steps each.
// ---------------------------------------------------------------------------
__global__ __launch_bounds__(64) void vit_back_kernel(
    const uint8_t* __restrict__ bpg, const uint8_t* __restrict__ gmapg,
    const int* __restrict__ meta, float* __restrict__ out)
{
    const int tid = threadIdx.x;
    __shared__ uint8_t bps[TT * NT];     // 63488 B
    __shared__ uint8_t gm[32 * 32];
    __shared__ uint8_t echk[32];

    const uint32_t* src = (const uint32_t*)bpg;
    uint32_t* dst = (uint32_t*)bps;
    for (int i = tid; i < TT * NT / 4; i += 64) dst[i] = src[i];
    for (int i = tid; i < 1024 / 4; i += 64)
        ((uint32_t*)gm)[i] = ((const uint32_t*)gmapg)[i];
    __syncthreads();

    if (tid == 0) {
        int tag = meta[0];
        for (int b = 31; b >= 0; b--) { echk[b] = (uint8_t)tag; tag = gm[b * 32 + tag]; }
    }
    __syncthreads();
    if (tid < 32) {
        int tag = echk[tid];
        for (int i = 63; i >= 0; i--) {
            int t = tid * 64 + i;
            out[1 + t] = (float)tag;
            tag = bps[t * NT + tag];
        }
    }
}

// ---------------------------------------------------------------------------
extern "C" void kernel_launch(void* const* d_in, const int* in_sizes, int n_in,
                              void* d_out, int out_size, void* d_ws, size_t ws_size,
                              hipStream_t stream) {
    const float* sent   = (const float*)d_in[0];
    const float* mask   = (const float*)d_in[1];
    const float* w_ih_f = (const float*)d_in[2];
    const float* w_hh_f = (const float*)d_in[3];
    const float* b_ih_f = (const float*)d_in[4];
    const float* b_hh_f = (const float*)d_in[5];
    const float* w_ih_b = (const float*)d_in[6];
    const float* w_hh_b = (const float*)d_in[7];
    const float* b_ih_b = (const float*)d_in[8];
    const float* b_hh_b = (const float*)d_in[9];
    const float* w_out  = (const float*)d_in[10];
    const float* b_out  = (const float*)d_in[11];
    const float* trans  = (const float*)d_in[12];
    const int*   seqp   = (const int*)d_in[14];
    float* out = (float*)d_out;

    // ws layout (floats): gi[2*TT*300] | pfeat[2*TT*31] | fvg[(TT+1)*64] |
    //                     bpg (TT*31 bytes) | gmapg (1024 bytes) | meta
    float* gi    = (float*)d_ws;
    float* pfeat = gi + (size_t)2 * TT * GG;
    float* fvg   = pfeat + (size_t)2 * TT * NT;
    float* bpf   = fvg + (size_t)(TT + 1) * 64;
    uint8_t* bpg   = (uint8_t*)bpf;
    uint8_t* gmapg = bpg + (size_t)TT * NT;
    int*     meta  = (int*)(gmapg + 1024);

    gi_kernel<<<dim3(TT, 2), 320, 0, stream>>>(sent, seqp, w_ih_f, b_ih_f,
                                               w_ih_b, b_ih_b, gi);
    gru_seq_kernel<<<2, 256, 0, stream>>>(gi, w_hh_f, b_hh_f, w_hh_b, b_hh_b,
                                          w_out, pfeat);
    vit_scan_kernel<<<1, 64, 0, stream>>>(pfeat, mask, seqp, trans, b_out,
                                          fvg, meta, out);
    vit_bp_kernel<<<32, 1024, 0, stream>>>(fvg, mask, seqp, trans, bpg, gmapg);
    vit_back_kernel<<<1, 64, 0, stream>>>(bpg, gmapg, meta, out);
}